// Round 13
// baseline (13515.410 us; speedup 1.0000x reference)
//
#include <hip/hip_runtime.h>

// Shapes (fixed by the problem)
#define BATCH 256
#define ENCH  512   // encoder hidden (e)
#define WWID  256   // encoder width  (w)
#define ATT   256   // attn size      (a)
#define DECH  256   // decoder hidden (d)
#define EMBD  128
#define VOC   81
#define TT    100

// ---------- numerics: fp32 everywhere, libm-grade (trajectory-critical) ------
__device__ __forceinline__ float ftanh(float x) {
  float e = expf(2.0f * x);
  return 1.0f - 2.0f / (e + 1.0f);
}
__device__ __forceinline__ float fsig(float x) {
  return 1.0f / (1.0f + expf(-x));
}

// ------------- build transposed weights: W2[k][g], DW2[k][a] -----------------
__global__ void k_build(const float* __restrict__ w_ih, const float* __restrict__ w_hh,
                        const float* __restrict__ dlw,
                        float* __restrict__ W2, float* __restrict__ DW2) {
  int k = blockIdx.x, tid = threadIdx.x;
  if (k < 768) {
    for (int g = tid; g < 1024; g += 256)
      W2[(size_t)k * 1024 + g] = (k < 512) ? w_ih[(size_t)g * 640 + 128 + k]
                                           : w_hh[(size_t)g * 256 + (k - 512)];
  } else {
    int kk = k - 768;
    DW2[kk * 256 + tid] = dlw[tid * 256 + kk];
  }
}

// ---------- emb_gates[v][g] = b_ih[g]+b_hh[g] + sum_e emb[v][e] w_ih[g][e] ---
__global__ void k_embg(const float* __restrict__ emb, const float* __restrict__ w_ih,
                       const float* __restrict__ b_ih, const float* __restrict__ b_hh,
                       float* __restrict__ embg) {
  int v = blockIdx.x, tid = threadIdx.x;
  __shared__ float em[EMBD];
  if (tid < EMBD) em[tid] = emb[v * EMBD + tid];
  __syncthreads();
  for (int g = tid; g < 1024; g += 256) {
    float s = b_ih[g] + b_hh[g];
    const float* wr = w_ih + (size_t)g * 640;
#pragma unroll 8
    for (int e = 0; e < EMBD; ++e) s += em[e] * wr[e];
    embg[v * 1024 + g] = s;
  }
}

// ------------- weighted_enc[b][a][w] = sum_e cw[a][e] enc[b][e][w] + cb[a] ----
__global__ void __launch_bounds__(256) k_we(const float* __restrict__ enc,
                                            const float* __restrict__ cw,
                                            const float* __restrict__ cb,
                                            float* __restrict__ we) {
  int bid = blockIdx.x;
  int b = bid >> 4, at = (bid >> 2) & 3, wt = bid & 3;
  int a0 = at * 64, w0 = wt * 64;
  __shared__ float cwT[32][68];
  __shared__ float encT[32][64];
  int tid = threadIdx.x;
  int tx = tid & 15, ty = tid >> 4;
  float acc[4][4] = {};
  const float* encB = enc + (size_t)b * ENCH * WWID;
  for (int k0 = 0; k0 < ENCH; k0 += 32) {
    {
      int a = tid >> 2, e8 = (tid & 3) * 8;
      const float* src = cw + (size_t)(a0 + a) * ENCH + k0 + e8;
      float4 v0 = *(const float4*)(src);
      float4 v1 = *(const float4*)(src + 4);
      cwT[e8 + 0][a] = v0.x; cwT[e8 + 1][a] = v0.y; cwT[e8 + 2][a] = v0.z; cwT[e8 + 3][a] = v0.w;
      cwT[e8 + 4][a] = v1.x; cwT[e8 + 5][a] = v1.y; cwT[e8 + 6][a] = v1.z; cwT[e8 + 7][a] = v1.w;
    }
    {
      int e = tid >> 3, w8 = (tid & 7) * 8;
      const float* src = encB + (size_t)(k0 + e) * WWID + w0 + w8;
      *(float4*)&encT[e][w8] = *(const float4*)src;
      *(float4*)&encT[e][w8 + 4] = *(const float4*)(src + 4);
    }
    __syncthreads();
#pragma unroll
    for (int e = 0; e < 32; ++e) {
      float4 av = *(const float4*)&cwT[e][ty * 4];
      float4 bv = *(const float4*)&encT[e][tx * 4];
      float a4[4] = {av.x, av.y, av.z, av.w};
      float b4[4] = {bv.x, bv.y, bv.z, bv.w};
#pragma unroll
      for (int i = 0; i < 4; ++i)
#pragma unroll
        for (int j = 0; j < 4; ++j) acc[i][j] += a4[i] * b4[j];
    }
    __syncthreads();
  }
#pragma unroll
  for (int i = 0; i < 4; ++i) {
    int a = a0 + ty * 4 + i;
    float bias = cb[a];
    float4 o;
    o.x = acc[i][0] + bias; o.y = acc[i][1] + bias;
    o.z = acc[i][2] + bias; o.w = acc[i][3] + bias;
    *(float4*)(we + ((size_t)(b * ATT + a)) * WWID + w0 + tx * 4) = o;
  }
}

// =============== persistent per-batch kernel: all 100 steps ==================
// grid 256 blocks (one per batch) x 1024 threads (16 waves/CU).
// Numerics bit-identical to round 6 (+ validated dp 4-slice). NEW: no global
// stores inside the hot phases — alphas/logp/preds live in LDS and are flushed
// ONCE at step end with full-line float4 cached stores. This removes the
// write-allocate reads + read-stream eviction that r12's FETCH delta exposed,
// without r12's NT-store ack stalls.
__global__ void __launch_bounds__(1024, 1) k_loop(
    const float* __restrict__ we, const float* __restrict__ enc,
    const float* __restrict__ W2, const float* __restrict__ DW2,
    const float* __restrict__ embg, const float* __restrict__ dlb,
    const float* __restrict__ ew, const float* __restrict__ eb,
    const float* __restrict__ ow, const float* __restrict__ ob,
    const int* __restrict__ sos, float* __restrict__ out) {
  const int tid = threadIdx.x;
  const int b = blockIdx.x;

  __shared__ float xf_s[768];              // x = [ctx(0..511) | h(512..767)]
  __shared__ float c_s[256];
  __shared__ float dp_s[256], ew_s[256], sc_s[256];
  __shared__ float partA[16][64][4];       // 16 KB
  __shared__ float partDP[4][256];         // 4 KB
  __shared__ float gpre_s[1024];
  __shared__ float red[8];
  __shared__ float lg[VOC], lp_s[VOC];
  __shared__ int xcur;

  if (tid < 256) {
    ew_s[tid] = ew[tid];
    c_s[tid] = 0.0f;
    xf_s[512 + tid] = 0.0f;                // h(-1) = 0
  }
  if (tid == 0) xcur = sos[0];
  const float ebv = eb[0];
  const float* weB = we + ((size_t)b << 16);
  const float* encB = enc + (size_t)b * ENCH * WWID;
  const int q = tid & 63, pt = tid >> 6;   // lane, wave
  __syncthreads();

  for (int t = 0; t < TT; ++t) {
    // ---------- dp[a]: 4 k-slices of 64 across 16 waves (validated r9-r12) ---
    {
      int a = tid & 255, s = tid >> 8;
      float acc = 0.0f;
      const float* dw = DW2 + a;
      const float* hs = &xf_s[512];
      int k0 = s * 64;
#pragma unroll 8
      for (int k = k0; k < k0 + 64; ++k) acc += dw[k * 256] * hs[k];
      partDP[s][a] = acc;
    }
    __syncthreads();
    if (tid < 256) {
      dp_s[tid] = dlb[tid] + partDP[0][tid] + partDP[1][tid] +
                  partDP[2][tid] + partDP[3][tid];
    }
    __syncthreads();
    // ---------- scores: 16 waves x 16 a-rows (exact r6 order) ----------------
    {
      float s0 = 0, s1 = 0, s2 = 0, s3 = 0;
      int abase = pt * 16;
#pragma unroll 4
      for (int i = 0; i < 16; ++i) {
        int aa = abase + i;
        float4 wv = *(const float4*)(weB + (size_t)aa * 256 + q * 4);
        float d = dp_s[aa], w8 = ew_s[aa];
        s0 += w8 * ftanh(wv.x + d);
        s1 += w8 * ftanh(wv.y + d);
        s2 += w8 * ftanh(wv.z + d);
        s3 += w8 * ftanh(wv.w + d);
      }
      partA[pt][q][0] = s0; partA[pt][q][1] = s1;
      partA[pt][q][2] = s2; partA[pt][q][3] = s3;
    }
    __syncthreads();
    // ---------- softmax over w (256)  (exact r6 order; NO global store) ------
    float sv = 0.0f;
    if (tid < 256) {
      sv = ebv;
#pragma unroll
      for (int p = 0; p < 16; ++p) sv += partA[p][tid >> 2][tid & 3];
      float mm = sv;
      for (int off = 32; off; off >>= 1) mm = fmaxf(mm, __shfl_xor(mm, off));
      if ((tid & 63) == 0) red[tid >> 6] = mm;
    }
    __syncthreads();
    float mA = fmaxf(fmaxf(red[0], red[1]), fmaxf(red[2], red[3]));
    float pa = 0.0f;
    if (tid < 256) {
      pa = expf(sv - mA);
      float ss = pa;
      for (int off = 32; off; off >>= 1) ss += __shfl_xor(ss, off);
      if ((tid & 63) == 0) red[4 + (tid >> 6)] = ss;
    }
    __syncthreads();
    {
      float S = red[4] + red[5] + red[6] + red[7];
      if (tid < 256) sc_s[tid] = pa / S;    // alpha stays in LDS until flush
    }
    __syncthreads();
    // ---------- context[e]: e-order identical to r6, 8-deep prefetch ---------
    {
      int lane = tid & 63, wvi = tid >> 6;
      float4 al = *(const float4*)&sc_s[lane * 4];
#pragma unroll
      for (int g = 0; g < 4; ++g) {
        float4 ev[8];
#pragma unroll
        for (int j = 0; j < 8; ++j) {
          int e = wvi + (g * 8 + j) * 16;
          ev[j] = *(const float4*)(encB + (size_t)e * WWID + lane * 4);
        }
#pragma unroll
        for (int j = 0; j < 8; ++j) {
          int e = wvi + (g * 8 + j) * 16;
          float s = ev[j].x * al.x + ev[j].y * al.y + ev[j].z * al.z + ev[j].w * al.w;
          for (int off = 32; off; off >>= 1) s += __shfl_xor(s, off);
          if (lane == 0) xf_s[e] = s;
        }
      }
    }
    __syncthreads();
    // ---------- gates GEMV: 1 thread/column, K=768 seq (exact r6 form) -------
    {
      float acc = 0.0f;
      const float* w0 = W2 + tid;
#pragma unroll 2
      for (int k4 = 0; k4 < 192; ++k4) {
        float4 xv = *(const float4*)&xf_s[k4 * 4];
        const float* wp = w0 + (size_t)k4 * 4096;
        acc += wp[0] * xv.x + wp[1024] * xv.y + wp[2048] * xv.z + wp[3072] * xv.w;
      }
      gpre_s[tid] = acc + embg[(size_t)xcur * 1024 + tid];
    }
    __syncthreads();
    // ---------- LSTM cell  (exact r6 values) ---------------------------------
    if (tid < 256) {
      float iv = fsig(gpre_s[tid]);
      float fv = fsig(gpre_s[256 + tid]);
      float gv = ftanh(gpre_s[512 + tid]);
      float ov = fsig(gpre_s[768 + tid]);
      float cn = fv * c_s[tid] + iv * gv;
      float hn = ov * ftanh(cn);
      c_s[tid] = cn;
      xf_s[512 + tid] = hn;               // h(t)
    }
    __syncthreads();
    // ---------- logits + log_softmax + argmax  (exact r6 order) --------------
    {
      int lane = tid & 63, wv = tid >> 6;
      float4 hh = *(const float4*)&xf_s[512 + lane * 4];
      for (int v = wv; v < VOC; v += 16) {
        float4 wr = *(const float4*)(ow + (size_t)v * 256 + lane * 4);
        float s = wr.x * hh.x + wr.y * hh.y + wr.z * hh.z + wr.w * hh.w;
        for (int off = 32; off; off >>= 1) s += __shfl_xor(s, off);
        if (lane == 0) lg[v] = s + ob[v];
      }
    }
    __syncthreads();
    float v_ = -3.402823e38f, pe = 0.0f;
    if (tid < 256) {
      v_ = (tid < VOC) ? lg[tid] : -3.402823e38f;
      float mm = v_;
      for (int off = 32; off; off >>= 1) mm = fmaxf(mm, __shfl_xor(mm, off));
      if ((tid & 63) == 0) red[tid >> 6] = mm;
    }
    __syncthreads();
    float mC = fmaxf(fmaxf(red[0], red[1]), fmaxf(red[2], red[3]));
    if (tid < 256) {
      pe = (tid < VOC) ? expf(v_ - mC) : 0.0f;
      float ss = pe;
      for (int off = 32; off; off >>= 1) ss += __shfl_xor(ss, off);
      if ((tid & 63) == 0) red[4 + (tid >> 6)] = ss;
    }
    __syncthreads();
    {
      float S = red[4] + red[5] + red[6] + red[7];
      float lse = mC + logf(S);
      if (tid < VOC) lp_s[tid] = v_ - lse;  // logp stays in LDS until flush
    }
    __syncthreads();
    if (tid == 0) {
      int best = 0;
      float bv = lp_s[0];
      for (int v = 1; v < VOC; ++v) {
        float x = lp_s[v];
        if (x > bv) { bv = x; best = v; }
      }
      xcur = best;
    }
    __syncthreads();
    // ---------- step-end flush: full-line float4 cached stores ---------------
    // Overlaps the next step's dp phase; sc_s/lp_s/xcur are not rewritten
    // until >=2 barriers into the next step.
    if (tid < 64) {          // attns: 1 KB = 8 full 128B lines
      *(float4*)&out[(size_t)(BATCH * TT * VOC) + (size_t)(BATCH * TT) +
                     ((size_t)b * TT + t) * WWID + tid * 4] =
          *(const float4*)&sc_s[tid * 4];
    } else if (tid < 84) {   // logp: 20 x float4
      int i = tid - 64;
      *(float4*)&out[((size_t)b * TT + t) * VOC + i * 4] =
          *(const float4*)&lp_s[i * 4];
    } else if (tid == 84) {  // logp tail element 80
      out[((size_t)b * TT + t) * VOC + 80] = lp_s[80];
    } else if (tid == 85) {  // preds
      out[(size_t)(BATCH * TT * VOC) + (size_t)b * TT + t] = (float)xcur;
    }
  }
}

extern "C" void kernel_launch(void* const* d_in, const int* in_sizes, int n_in,
                              void* d_out, int out_size, void* d_ws, size_t ws_size,
                              hipStream_t stream) {
  (void)in_sizes; (void)n_in; (void)out_size; (void)ws_size;
  const float* enc = (const float*)d_in[0];
  const float* emb = (const float*)d_in[1];
  const float* ecw = (const float*)d_in[2];
  const float* ecb = (const float*)d_in[3];
  const float* dlw = (const float*)d_in[4];
  const float* dlb = (const float*)d_in[5];
  const float* ew  = (const float*)d_in[6];
  const float* eb  = (const float*)d_in[7];
  const float* wih = (const float*)d_in[8];
  const float* whh = (const float*)d_in[9];
  const float* bih = (const float*)d_in[10];
  const float* bhh = (const float*)d_in[11];
  const float* ow  = (const float*)d_in[12];
  const float* ob  = (const float*)d_in[13];
  const int* sos   = (const int*)d_in[15];
  float* out = (float*)d_out;
  float* ws = (float*)d_ws;

  // workspace map (floats); ~17.7M floats ~ 71 MB
  size_t off = 0;
  float* we    = ws + off; off += (size_t)BATCH * ATT * WWID;  // 16,777,216
  float* W2    = ws + off; off += (size_t)768 * 1024;
  float* DW2   = ws + off; off += (size_t)256 * 256;
  float* embg  = ws + off; off += (size_t)VOC * 1024;

  k_build<<<1024, 256, 0, stream>>>(wih, whh, dlw, W2, DW2);
  k_embg<<<VOC, 256, 0, stream>>>(emb, wih, bih, bhh, embg);
  k_we<<<4096, 256, 0, stream>>>(enc, ecw, ecb, we);
  k_loop<<<256, 1024, 0, stream>>>(we, enc, W2, DW2, embg, dlb, ew, eb, ow, ob,
                                   sos, out);
}

// Round 14
// 9175.997 us; speedup vs baseline: 1.4729x; 1.4729x over previous
//
#include <hip/hip_runtime.h>

// Shapes (fixed by the problem)
#define BATCH 256
#define ENCH  512   // encoder hidden (e)
#define WWID  256   // encoder width  (w)
#define ATT   256   // attn size      (a)
#define DECH  256   // decoder hidden (d)
#define EMBD  128
#define VOC   81
#define TT    100

// ---------- numerics: fp32 everywhere, libm-grade (trajectory-critical) ------
__device__ __forceinline__ float ftanh(float x) {
  float e = expf(2.0f * x);
  return 1.0f - 2.0f / (e + 1.0f);
}
__device__ __forceinline__ float fsig(float x) {
  return 1.0f / (1.0f + expf(-x));
}

// async global->LDS copy, 4B per lane, wave-uniform LDS base (HW adds lane*4)
__device__ __forceinline__ void gl_lds4(const float* gsrc, float* ldst) {
  typedef const __attribute__((address_space(1))) void* gas_t;
  typedef __attribute__((address_space(3))) void* las_t;
  __builtin_amdgcn_global_load_lds((gas_t)(const void*)gsrc, (las_t)(void*)ldst,
                                   4, 0, 0);
}

// ------------- build transposed weights: W2[k][g], DW2[k][a] -----------------
__global__ void k_build(const float* __restrict__ w_ih, const float* __restrict__ w_hh,
                        const float* __restrict__ dlw,
                        float* __restrict__ W2, float* __restrict__ DW2) {
  int k = blockIdx.x, tid = threadIdx.x;
  if (k < 768) {
    for (int g = tid; g < 1024; g += 256)
      W2[(size_t)k * 1024 + g] = (k < 512) ? w_ih[(size_t)g * 640 + 128 + k]
                                           : w_hh[(size_t)g * 256 + (k - 512)];
  } else {
    int kk = k - 768;
    DW2[kk * 256 + tid] = dlw[tid * 256 + kk];
  }
}

// ---------- emb_gates[v][g] = b_ih[g]+b_hh[g] + sum_e emb[v][e] w_ih[g][e] ---
__global__ void k_embg(const float* __restrict__ emb, const float* __restrict__ w_ih,
                       const float* __restrict__ b_ih, const float* __restrict__ b_hh,
                       float* __restrict__ embg) {
  int v = blockIdx.x, tid = threadIdx.x;
  __shared__ float em[EMBD];
  if (tid < EMBD) em[tid] = emb[v * EMBD + tid];
  __syncthreads();
  for (int g = tid; g < 1024; g += 256) {
    float s = b_ih[g] + b_hh[g];
    const float* wr = w_ih + (size_t)g * 640;
#pragma unroll 8
    for (int e = 0; e < EMBD; ++e) s += em[e] * wr[e];
    embg[v * 1024 + g] = s;
  }
}

// ------------- weighted_enc[b][a][w] = sum_e cw[a][e] enc[b][e][w] + cb[a] ----
__global__ void __launch_bounds__(256) k_we(const float* __restrict__ enc,
                                            const float* __restrict__ cw,
                                            const float* __restrict__ cb,
                                            float* __restrict__ we) {
  int bid = blockIdx.x;
  int b = bid >> 4, at = (bid >> 2) & 3, wt = bid & 3;
  int a0 = at * 64, w0 = wt * 64;
  __shared__ float cwT[32][68];
  __shared__ float encT[32][64];
  int tid = threadIdx.x;
  int tx = tid & 15, ty = tid >> 4;
  float acc[4][4] = {};
  const float* encB = enc + (size_t)b * ENCH * WWID;
  for (int k0 = 0; k0 < ENCH; k0 += 32) {
    {
      int a = tid >> 2, e8 = (tid & 3) * 8;
      const float* src = cw + (size_t)(a0 + a) * ENCH + k0 + e8;
      float4 v0 = *(const float4*)(src);
      float4 v1 = *(const float4*)(src + 4);
      cwT[e8 + 0][a] = v0.x; cwT[e8 + 1][a] = v0.y; cwT[e8 + 2][a] = v0.z; cwT[e8 + 3][a] = v0.w;
      cwT[e8 + 4][a] = v1.x; cwT[e8 + 5][a] = v1.y; cwT[e8 + 6][a] = v1.z; cwT[e8 + 7][a] = v1.w;
    }
    {
      int e = tid >> 3, w8 = (tid & 7) * 8;
      const float* src = encB + (size_t)(k0 + e) * WWID + w0 + w8;
      *(float4*)&encT[e][w8] = *(const float4*)src;
      *(float4*)&encT[e][w8 + 4] = *(const float4*)(src + 4);
    }
    __syncthreads();
#pragma unroll
    for (int e = 0; e < 32; ++e) {
      float4 av = *(const float4*)&cwT[e][ty * 4];
      float4 bv = *(const float4*)&encT[e][tx * 4];
      float a4[4] = {av.x, av.y, av.z, av.w};
      float b4[4] = {bv.x, bv.y, bv.z, bv.w};
#pragma unroll
      for (int i = 0; i < 4; ++i)
#pragma unroll
        for (int j = 0; j < 4; ++j) acc[i][j] += a4[i] * b4[j];
    }
    __syncthreads();
  }
#pragma unroll
  for (int i = 0; i < 4; ++i) {
    int a = a0 + ty * 4 + i;
    float bias = cb[a];
    float4 o;
    o.x = acc[i][0] + bias; o.y = acc[i][1] + bias;
    o.z = acc[i][2] + bias; o.w = acc[i][3] + bias;
    *(float4*)(we + ((size_t)(b * ATT + a)) * WWID + w0 + tx * 4) = o;
  }
}

// =============== persistent per-batch kernel: all 100 steps ==================
// EXACT round-6 kernel (8.78 ms best baseline) with ONE change: the gates
// GEMV streams W2 through a per-wave async LDS pipeline (global_load_lds
// width-4, 8-row tiles, 4 buffers/wave, counted s_waitcnt vmcnt — no
// barriers, no vmcnt(0) drains, no data VGPRs). FMA order per column is
// byte-identical to r6. Everything else is r6 text.
__global__ void __launch_bounds__(1024, 1) k_loop(
    const float* __restrict__ we, const float* __restrict__ enc,
    const float* __restrict__ W2, const float* __restrict__ DW2,
    const float* __restrict__ embg, const float* __restrict__ dlb,
    const float* __restrict__ ew, const float* __restrict__ eb,
    const float* __restrict__ ow, const float* __restrict__ ob,
    const int* __restrict__ sos, float* __restrict__ out) {
  const int tid = threadIdx.x;
  const int b = blockIdx.x;

  __shared__ float w2lds[16 * 4 * 512];    // 128 KB: per-wave 4-buf W2 tiles
  __shared__ float xf_s[768];              // x = [ctx(0..511) | h(512..767)]
  __shared__ float c_s[256];
  __shared__ float dp_s[256], ew_s[256], sc_s[256];
  __shared__ float partA[16][64][4];       // 16 KB
  __shared__ float gpre_s[1024];
  __shared__ float red[8];
  __shared__ float lg[VOC], lp_s[VOC];
  __shared__ int xcur;

  if (tid < 256) {
    ew_s[tid] = ew[tid];
    c_s[tid] = 0.0f;
    xf_s[512 + tid] = 0.0f;                // h(-1) = 0
  }
  if (tid == 0) xcur = sos[0];
  const float ebv = eb[0];
  const float* weB = we + ((size_t)b << 16);
  const float* encB = enc + (size_t)b * ENCH * WWID;
  const int q = tid & 63, pt = tid >> 6;   // lane, wave
  __syncthreads();

  for (int t = 0; t < TT; ++t) {
    // ---------- dp[a] = dlb[a] + sum_k h[k] * DW2[k][a]  (exact r6) ----------
    if (tid < 256) {
      float acc = dlb[tid];
      const float* dw = DW2 + tid;
#pragma unroll 8
      for (int k = 0; k < DECH; ++k) acc += dw[k * 256] * xf_s[512 + k];
      dp_s[tid] = acc;
    }
    __syncthreads();
    // ---------- scores: 16 waves x 16 a-rows (exact r6) ----------------------
    {
      float s0 = 0, s1 = 0, s2 = 0, s3 = 0;
      int abase = pt * 16;
#pragma unroll 4
      for (int i = 0; i < 16; ++i) {
        int aa = abase + i;
        float4 wv = *(const float4*)(weB + (size_t)aa * 256 + q * 4);
        float d = dp_s[aa], w8 = ew_s[aa];
        s0 += w8 * ftanh(wv.x + d);
        s1 += w8 * ftanh(wv.y + d);
        s2 += w8 * ftanh(wv.z + d);
        s3 += w8 * ftanh(wv.w + d);
      }
      partA[pt][q][0] = s0; partA[pt][q][1] = s1;
      partA[pt][q][2] = s2; partA[pt][q][3] = s3;
    }
    __syncthreads();
    // ---------- softmax over w (256)  (exact r6) -----------------------------
    float sv = 0.0f;
    if (tid < 256) {
      sv = ebv;
#pragma unroll
      for (int p = 0; p < 16; ++p) sv += partA[p][tid >> 2][tid & 3];
      float mm = sv;
      for (int off = 32; off; off >>= 1) mm = fmaxf(mm, __shfl_xor(mm, off));
      if ((tid & 63) == 0) red[tid >> 6] = mm;
    }
    __syncthreads();
    float mA = fmaxf(fmaxf(red[0], red[1]), fmaxf(red[2], red[3]));
    float pa = 0.0f;
    if (tid < 256) {
      pa = expf(sv - mA);
      float ss = pa;
      for (int off = 32; off; off >>= 1) ss += __shfl_xor(ss, off);
      if ((tid & 63) == 0) red[4 + (tid >> 6)] = ss;
    }
    __syncthreads();
    {
      float S = red[4] + red[5] + red[6] + red[7];
      if (tid < 256) {
        float alpha = pa / S;
        sc_s[tid] = alpha;
        out[(size_t)(BATCH * TT * VOC) + (size_t)(BATCH * TT) +
            ((size_t)b * TT + t) * WWID + tid] = alpha;
      }
    }
    __syncthreads();
    // ---------- context[e] (exact r6) ----------------------------------------
    {
      int lane = tid & 63, wvi = tid >> 6;
      float4 al = *(const float4*)&sc_s[lane * 4];
#pragma unroll 4
      for (int e = wvi; e < ENCH; e += 16) {
        float4 evv = *(const float4*)(encB + (size_t)e * WWID + lane * 4);
        float s = evv.x * al.x + evv.y * al.y + evv.z * al.z + evv.w * al.w;
        for (int off = 32; off; off >>= 1) s += __shfl_xor(s, off);
        if (lane == 0) xf_s[e] = s;
      }
    }
    __syncthreads();   // drains vmcnt(0): gates region starts with clean count
    // ---------- gates GEMV: per-wave async W2 pipeline (NEW) -----------------
    // 96 tiles of 8 rows; wave stages ONLY its 64 columns (256 B/row, width-4
    // global_load_lds); 4 LDS buffers/wave; counted vmcnt keeps 2 tiles in
    // flight. Per-column FMA order identical to r6.
    {
      float eg = embg[(size_t)xcur * 1024 + tid];
      asm volatile("s_waitcnt vmcnt(0)" ::: "memory");   // retire eg: clean count
      __builtin_amdgcn_sched_barrier(0);
      float* wl = w2lds + pt * 2048;       // this wave's 4x512 region
      const float* wsrc = W2 + pt * 64 + q;
      float acc = 0.0f;
#pragma unroll
      for (int i0 = 0; i0 < 3; ++i0) {     // prologue: stage tiles 0..2
        const float* src = wsrc + (size_t)(i0 * 8) * 1024;
        float* dst = wl + i0 * 512;
#pragma unroll
        for (int r = 0; r < 8; ++r)
          gl_lds4(src + (size_t)r * 1024, dst + r * 64);
      }
      for (int i = 0; i < 96; ++i) {
        if (i < 94) {
          asm volatile("s_waitcnt vmcnt(16)" ::: "memory");
        } else if (i == 94) {
          asm volatile("s_waitcnt vmcnt(8)" ::: "memory");
        } else {
          asm volatile("s_waitcnt vmcnt(0)" ::: "memory");
        }
        __builtin_amdgcn_sched_barrier(0);
        const float* tl = wl + (i & 3) * 512;
#pragma unroll
        for (int r4 = 0; r4 < 2; ++r4) {   // k4 = i*2 + r4, sequential overall
          float4 xv = *(const float4*)&xf_s[(i * 2 + r4) * 4];
          acc += tl[(r4 * 4 + 0) * 64 + q] * xv.x +
                 tl[(r4 * 4 + 1) * 64 + q] * xv.y +
                 tl[(r4 * 4 + 2) * 64 + q] * xv.z +
                 tl[(r4 * 4 + 3) * 64 + q] * xv.w;
        }
        if (i + 3 < 96) {                  // stage tile i+3 into freed buffer
          const float* src = wsrc + (size_t)((i + 3) * 8) * 1024;
          float* dst = wl + ((i + 3) & 3) * 512;
#pragma unroll
          for (int r = 0; r < 8; ++r)
            gl_lds4(src + (size_t)r * 1024, dst + r * 64);
        }
      }
      gpre_s[tid] = acc + eg;
    }
    __syncthreads();
    // ---------- LSTM cell  (exact r6) ----------------------------------------
    if (tid < 256) {
      float iv = fsig(gpre_s[tid]);
      float fv = fsig(gpre_s[256 + tid]);
      float gv = ftanh(gpre_s[512 + tid]);
      float ov = fsig(gpre_s[768 + tid]);
      float cn = fv * c_s[tid] + iv * gv;
      float hn = ov * ftanh(cn);
      c_s[tid] = cn;
      xf_s[512 + tid] = hn;               // h(t)
    }
    __syncthreads();
    // ---------- logits + log_softmax + argmax  (exact r6) --------------------
    {
      int lane = tid & 63, wv = tid >> 6;
      float4 hh = *(const float4*)&xf_s[512 + lane * 4];
      for (int v = wv; v < VOC; v += 16) {
        float4 wr = *(const float4*)(ow + (size_t)v * 256 + lane * 4);
        float s = wr.x * hh.x + wr.y * hh.y + wr.z * hh.z + wr.w * hh.w;
        for (int off = 32; off; off >>= 1) s += __shfl_xor(s, off);
        if (lane == 0) lg[v] = s + ob[v];
      }
    }
    __syncthreads();
    float v_ = -3.402823e38f, pe = 0.0f;
    if (tid < 256) {
      v_ = (tid < VOC) ? lg[tid] : -3.402823e38f;
      float mm = v_;
      for (int off = 32; off; off >>= 1) mm = fmaxf(mm, __shfl_xor(mm, off));
      if ((tid & 63) == 0) red[tid >> 6] = mm;
    }
    __syncthreads();
    float mC = fmaxf(fmaxf(red[0], red[1]), fmaxf(red[2], red[3]));
    if (tid < 256) {
      pe = (tid < VOC) ? expf(v_ - mC) : 0.0f;
      float ss = pe;
      for (int off = 32; off; off >>= 1) ss += __shfl_xor(ss, off);
      if ((tid & 63) == 0) red[4 + (tid >> 6)] = ss;
    }
    __syncthreads();
    {
      float S = red[4] + red[5] + red[6] + red[7];
      float lse = mC + logf(S);
      if (tid < VOC) {
        float lp = v_ - lse;
        lp_s[tid] = lp;
        out[((size_t)b * TT + t) * VOC + tid] = lp;
      }
    }
    __syncthreads();
    if (tid == 0) {
      int best = 0;
      float bv = lp_s[0];
      for (int v = 1; v < VOC; ++v) {
        float x = lp_s[v];
        if (x > bv) { bv = x; best = v; }
      }
      xcur = best;
      out[(size_t)(BATCH * TT * VOC) + (size_t)b * TT + t] = (float)best;
    }
    __syncthreads();
  }
}

extern "C" void kernel_launch(void* const* d_in, const int* in_sizes, int n_in,
                              void* d_out, int out_size, void* d_ws, size_t ws_size,
                              hipStream_t stream) {
  (void)in_sizes; (void)n_in; (void)out_size; (void)ws_size;
  const float* enc = (const float*)d_in[0];
  const float* emb = (const float*)d_in[1];
  const float* ecw = (const float*)d_in[2];
  const float* ecb = (const float*)d_in[3];
  const float* dlw = (const float*)d_in[4];
  const float* dlb = (const float*)d_in[5];
  const float* ew  = (const float*)d_in[6];
  const float* eb  = (const float*)d_in[7];
  const float* wih = (const float*)d_in[8];
  const float* whh = (const float*)d_in[9];
  const float* bih = (const float*)d_in[10];
  const float* bhh = (const float*)d_in[11];
  const float* ow  = (const float*)d_in[12];
  const float* ob  = (const float*)d_in[13];
  const int* sos   = (const int*)d_in[15];
  float* out = (float*)d_out;
  float* ws = (float*)d_ws;

  // workspace map (floats); ~17.7M floats ~ 71 MB
  size_t off = 0;
  float* we    = ws + off; off += (size_t)BATCH * ATT * WWID;  // 16,777,216
  float* W2    = ws + off; off += (size_t)768 * 1024;
  float* DW2   = ws + off; off += (size_t)256 * 256;
  float* embg  = ws + off; off += (size_t)VOC * 1024;

  k_build<<<1024, 256, 0, stream>>>(wih, whh, dlw, W2, DW2);
  k_embg<<<VOC, 256, 0, stream>>>(emb, wih, bih, bhh, embg);
  k_we<<<4096, 256, 0, stream>>>(enc, ecw, ecb, we);
  k_loop<<<256, 1024, 0, stream>>>(we, enc, W2, DW2, embg, dlb, ew, eb, ow, ob,
                                   sos, out);
}